// Round 1
// baseline (282.043 us; speedup 1.0000x reference)
//
#include <hip/hip_runtime.h>
#include <hip/hip_bf16.h>
#include <cfloat>

#define TOKENS 16384   // B*N
#define DDIM   2048
#define NEXP   128
#define KTOP   8
#define MB     64      // tokens per block
#define KB     32      // k per LDS tile
#define NTILES (DDIM / KB)   // 64

// branchless sorted-insert into descending top-8 list.
// strict '>' => ties keep the earlier (lower) index, matching jax.lax.top_k.
__device__ __forceinline__ void insert8(float (&vals)[8], int (&idxs)[8], float v, int e) {
    bool c[8];
#pragma unroll
    for (int p = 0; p < 8; ++p) c[p] = v > vals[p];
#pragma unroll
    for (int p = 7; p >= 1; --p) {
        vals[p] = c[p] ? (c[p - 1] ? vals[p - 1] : v) : vals[p];
        idxs[p] = c[p] ? (c[p - 1] ? idxs[p - 1] : e) : idxs[p];
    }
    vals[0] = c[0] ? v : vals[0];
    idxs[0] = c[0] ? e : idxs[0];
}

__global__ __launch_bounds__(256, 1) void router_kernel(
    const float* __restrict__ x, const float* __restrict__ W,
    const float* __restrict__ b, float* __restrict__ out_gates,
    float* __restrict__ out_idx)
{
    // LDS: double-buffered GEMM tiles + epilogue scratch (total ~98 KiB)
    __shared__ float xs[2][MB * KB];     // x tile, float4-slot XOR swizzle
    __shared__ float ws[2][NEXP * KB];   // W tile, same swizzle
    __shared__ float lg[MB * 132];       // logits, padded stride 132
    __shared__ float plv[MB * 4 * 8];    // partial top-8 values
    __shared__ int   pli[MB * 4 * 8];    // partial top-8 indices

    const int tid  = threadIdx.x;
    const int w    = tid >> 6;
    const int lane = tid & 63;
    const int eg   = lane & 15;          // expert group 0..15
    const int tg   = lane >> 4;          // token group within wave 0..3
    const int tgg  = w * 4 + tg;         // global token group 0..15
    const int tok0 = blockIdx.x * MB;

    // bias for this thread's 8 experts (e = eg + 16*j)
    float bv[8];
#pragma unroll
    for (int j = 0; j < 8; ++j) bv[j] = b[eg + 16 * j];

    float acc[4][8];
#pragma unroll
    for (int i = 0; i < 4; ++i)
#pragma unroll
        for (int j = 0; j < 8; ++j) acc[i][j] = 0.0f;

    const float4* x4 = (const float4*)x;
    const float4* W4 = (const float4*)W;

    float4 sx[2], sw[4];   // staged registers (T14 async split)

    // ---- prologue: load + write tile 0 ----
#pragma unroll
    for (int r = 0; r < 2; ++r) {
        int idx = r * 256 + tid; int m = idx >> 3, q = idx & 7;
        sx[r] = x4[(size_t)(tok0 + m) * (DDIM / 4) + q];
    }
#pragma unroll
    for (int r = 0; r < 4; ++r) {
        int idx = r * 256 + tid; int e = idx >> 3, q = idx & 7;
        sw[r] = W4[(size_t)e * (DDIM / 4) + q];
    }
#pragma unroll
    for (int r = 0; r < 2; ++r) {
        int idx = r * 256 + tid; int m = idx >> 3, q = idx & 7;
        *(float4*)&xs[0][m * KB + 4 * (q ^ (m & 7))] = sx[r];
    }
#pragma unroll
    for (int r = 0; r < 4; ++r) {
        int idx = r * 256 + tid; int e = idx >> 3, q = idx & 7;
        *(float4*)&ws[0][e * KB + 4 * (q ^ (e & 7))] = sw[r];
    }
    __syncthreads();

    // ---- main K loop: issue loads(t+1) -> compute(t) -> ds_write(t+1) -> barrier ----
    for (int t = 0; t < NTILES; ++t) {
        const int cur = t & 1;
        const bool more = (t + 1) < NTILES;
        if (more) {
            const int kq0 = (t + 1) * (KB / 4);
#pragma unroll
            for (int r = 0; r < 2; ++r) {
                int idx = r * 256 + tid; int m = idx >> 3, q = idx & 7;
                sx[r] = x4[(size_t)(tok0 + m) * (DDIM / 4) + kq0 + q];
            }
#pragma unroll
            for (int r = 0; r < 4; ++r) {
                int idx = r * 256 + tid; int e = idx >> 3, q = idx & 7;
                sw[r] = W4[(size_t)e * (DDIM / 4) + kq0 + q];
            }
        }

        // compute on buffer `cur`
#pragma unroll
        for (int kq = 0; kq < KB / 4; ++kq) {
            float4 xv[4], wv[8];
#pragma unroll
            for (int i = 0; i < 4; ++i) {
                int m = tgg + 16 * i;
                xv[i] = *(const float4*)&xs[cur][m * KB + 4 * (kq ^ (m & 7))];
            }
#pragma unroll
            for (int j = 0; j < 8; ++j) {
                int e = eg + 16 * j;
                wv[j] = *(const float4*)&ws[cur][e * KB + 4 * (kq ^ (e & 7))];
            }
#pragma unroll
            for (int i = 0; i < 4; ++i)
#pragma unroll
                for (int j = 0; j < 8; ++j) {
                    acc[i][j] += xv[i].x * wv[j].x;
                    acc[i][j] += xv[i].y * wv[j].y;
                    acc[i][j] += xv[i].z * wv[j].z;
                    acc[i][j] += xv[i].w * wv[j].w;
                }
        }

        if (more) {
            const int nb = (t + 1) & 1;
#pragma unroll
            for (int r = 0; r < 2; ++r) {
                int idx = r * 256 + tid; int m = idx >> 3, q = idx & 7;
                *(float4*)&xs[nb][m * KB + 4 * (q ^ (m & 7))] = sx[r];
            }
#pragma unroll
            for (int r = 0; r < 4; ++r) {
                int idx = r * 256 + tid; int e = idx >> 3, q = idx & 7;
                *(float4*)&ws[nb][e * KB + 4 * (q ^ (e & 7))] = sw[r];
            }
        }
        __syncthreads();
    }

    // ---- epilogue: logits -> LDS (add bias) ----
#pragma unroll
    for (int i = 0; i < 4; ++i) {
        int m = tgg + 16 * i;
#pragma unroll
        for (int j = 0; j < 8; ++j)
            lg[m * 132 + eg + 16 * j] = acc[i][j] + bv[j];
    }
    __syncthreads();

    // ---- partial top-8: 4 threads per token, 32 experts each ----
    {
        int tt = tid >> 2, p = tid & 3;
        float vals[8]; int idxs[8];
#pragma unroll
        for (int k = 0; k < 8; ++k) { vals[k] = -FLT_MAX; idxs[k] = 0; }
        const float* row = &lg[tt * 132 + p * 32];
        for (int q = 0; q < 32; ++q) {
            insert8(vals, idxs, row[q], p * 32 + q);
        }
#pragma unroll
        for (int k = 0; k < 8; ++k) {
            plv[tid * 8 + k] = vals[k];
            pli[tid * 8 + k] = idxs[k];
        }
    }
    __syncthreads();

    // ---- merge + softmax + index output (1 thread per token) ----
    float g[8]; int fidx[8];
    const bool active = (tid < MB);
    if (active) {
        float vals[8]; int idxs[8];
#pragma unroll
        for (int k = 0; k < 8; ++k) { vals[k] = -FLT_MAX; idxs[k] = 0; }
        for (int p = 0; p < 4; ++p) {
#pragma unroll
            for (int k = 0; k < 8; ++k) {
                insert8(vals, idxs, plv[(tid * 4 + p) * 8 + k], pli[(tid * 4 + p) * 8 + k]);
            }
        }
        float mx = vals[0];
        float s = 0.0f;
#pragma unroll
        for (int k = 0; k < 8; ++k) { g[k] = __expf(vals[k] - mx); s += g[k]; }
        float inv = 1.0f / s;
#pragma unroll
        for (int k = 0; k < 8; ++k) { g[k] *= inv; fidx[k] = idxs[k]; }
        // indices written as float values (harness reads whole out buffer as f32)
#pragma unroll
        for (int k = 0; k < 8; ++k)
            out_idx[(size_t)(tok0 + tid) * KTOP + k] = (float)idxs[k];
    }
    // zero dense gate rows (all threads; lg no longer read)
    for (int f = tid; f < MB * 132; f += 256) lg[f] = 0.0f;
    __syncthreads();

    if (active) {
#pragma unroll
        for (int k = 0; k < 8; ++k) lg[tid * 132 + fidx[k]] = g[k];
    }
    __syncthreads();

    // ---- coalesced dense copy-out ----
    for (int f = tid; f < MB * (NEXP / 4); f += 256) {
        int m = f >> 5, e4 = f & 31;
        float4 v = *(const float4*)&lg[m * 132 + e4 * 4];
        ((float4*)out_gates)[(size_t)(tok0 + m) * (NEXP / 4) + e4] = v;
    }
}

extern "C" void kernel_launch(void* const* d_in, const int* in_sizes, int n_in,
                              void* d_out, int out_size, void* d_ws, size_t ws_size,
                              hipStream_t stream) {
    const float* x = (const float*)d_in[0];   // [B,N,D] f32
    const float* W = (const float*)d_in[1];   // [E,D]   f32
    const float* b = (const float*)d_in[2];   // [E]     f32

    float* out_gates = (float*)d_out;                       // [B,N,E] f32
    float* out_idx   = out_gates + (size_t)TOKENS * NEXP;   // [B,N,K] as f32

    dim3 grid(TOKENS / MB);   // 256 blocks = 1 per CU
    dim3 block(256);
    router_kernel<<<grid, block, 0, stream>>>(x, W, b, out_gates, out_idx);
}